// Round 5
// baseline (1617.115 us; speedup 1.0000x reference)
//
#include <hip/hip_runtime.h>
#include <hip/hip_fp16.h>

// Wavefront-pipelined 20-layer ReLU RNN for MI355X — round 17.
// Base = r16 (1105us, producer/consumer wave split). r16 halved LDS traffic
// + conflicts with ZERO time change -> throughput (LDS/MFMA/HBM) is NOT the
// gate; the step period is latency/choreography-bound: each per-step barrier
// waits for the latest wave. The protocol pollers (remote agent-scope loads,
// ~600-900cy) sat on tid64/tid128 = h-waves 1,2, and h-waves also carried
// export + staging work. Change: h-waves (0-3) now do ONLY the h-recurrence
// (lH reads, 32 MFMA, epilogue, lH writes). Everything else -> X-waves:
//  - polls: tid256 (prod), tid320 (cons); publishes: tid448
//  - ring export: X-threads only, 4 u64 each (2 ds_read_b128 + stores)
//  - ring staging (pfv loads + bufX writes): X-only, 16 u64/superstep
//  - XPh reads hoisted: all 4 steps read at j0 (xps[s&1] fully valid)
//  - s_setprio(1) pinned on h-waves (1 h + 1 X per SIMD -> arbitration)
// Arithmetic bit-identical to r12/r14/r16.

#define B_    128
#define T_    784
#define H_    256
#define L_    20
#define C_    10
#define G_    8      // batch slices
#define BM_   16     // batch rows per block
#define S_    4      // timesteps per superstep / ring slot
#define NS_   196    // T_/S_
#define SW_   280    // LDS row stride in halves (140 dwords = 12 mod 32)
#define XSW_  260    // xps row stride in halves (130 dwords = 2 mod 32)
#define RQWS_ 4096   // u64 words per ring slot (4 x 16 x 256 halves = 32KB)
#define TPB_  512
#define HW_   4      // h-waves (waves 0..3); waves 4..7 are X-waves
#define NT_   4      // 16-col n-tiles per wave (both roles)

typedef _Float16 v8h __attribute__((ext_vector_type(8)));
typedef _Float16 v4h __attribute__((ext_vector_type(4)));
typedef float    v4f __attribute__((ext_vector_type(4)));
typedef unsigned long long u64;

union U64H { u64 u; _Float16 h[4]; };

// LDS-ordering barrier: drain own ds ops, rendezvous. vmem stays in flight.
__device__ __forceinline__ void bar_lds() {
    asm volatile("s_waitcnt lgkmcnt(0)" ::: "memory");
    __builtin_amdgcn_s_barrier();
    asm volatile("" ::: "memory");
}
// Full drain barrier (once per superstep, top of j==1): all waves' ring
// exports (slot s-1) complete -> safe to publish myprod=s after it.
__device__ __forceinline__ void bar_full() {
    asm volatile("s_waitcnt vmcnt(0) lgkmcnt(0)" ::: "memory");
    __builtin_amdgcn_s_barrier();
    asm volatile("" ::: "memory");
}

__global__ __launch_bounds__(TPB_, 2)
void rnn_wavefront(const float* __restrict__ x,
                   const float* __restrict__ W_ih0,
                   const float* __restrict__ b_ih0,
                   const float* __restrict__ W_ih,
                   const float* __restrict__ b_ih,
                   const float* __restrict__ W_hh,
                   const float* __restrict__ b_hh,
                   const float* __restrict__ W_fc,
                   const float* __restrict__ b_fc,
                   float* __restrict__ out,
                   unsigned* __restrict__ prod,    // [L_][G_] supersteps complete
                   unsigned* __restrict__ cons,    // [L_][G_] supersteps consumed
                   u64* __restrict__ ring,         // [L_][G_][R][RQWS_]
                   int rmask)                      // R-1, R power of two
{
    const int l    = blockIdx.x >> 3;
    const int g    = blockIdx.x & 7;
    const int tid  = threadIdx.x;
    const int lane = tid & 63;
    const int wave = tid >> 6;          // 0..7
    const bool hwv = wave < HW_;        // h-wave vs X-wave
    const int wsub = hwv ? wave : wave - HW_;
    const int quad = lane >> 4;
    const int s16  = lane & 15;
    const int nbase = wsub * 64;        // 64 output columns per wave (both roles)

    // X-thread export/staging mapping: 256 X-threads cover 16 rows x 16
    // col-chunks; each handles 4 consecutive u64 (32B) of a row.
    const int xtid = tid & 255;
    const int m_e  = xtid >> 4;         // row 0..15
    const int c_e  = xtid & 15;         // col chunk 0..15
    const int n_e  = c_e * 16;          // half offset (32B chunk)
    const size_t eidx = (size_t)m_e * 64 + (size_t)c_e * 4;  // u64 idx in slot-step

    // slot q lives in bufX[q&1]; staged during superstep q-2.
    __shared__ __align__(16) _Float16 bufX[2][S_][BM_][SW_];
    __shared__ __align__(16) _Float16 lH[2][BM_][SW_];     // own h, ping-pong
    // xps[p][jj][m][n]: XP for superstep s (p = s&1), f16, written by X-waves
    // during superstep s-1, read by h-waves during superstep s.
    __shared__ __align__(16) _Float16 xps[2][S_][BM_][XSW_];

    for (int i = tid; i < 2 * BM_ * SW_; i += TPB_) (&lH[0][0][0])[i] = (_Float16)0.f;

    // ---- weight fragments: role-split. h-waves: W_hh rows nbase..+63.
    // X-waves: W_ih (l>0). Lane holds W[n = nbase+nt*16+s16][k = kt*32+quad*8..]
    v8h wf[8][NT_];
#pragma unroll
    for (int kt = 0; kt < 8; ++kt) {
        const int k0 = kt * 32 + quad * 8;
#pragma unroll
        for (int nt = 0; nt < NT_; ++nt) {
            const int j = nbase + nt * 16 + s16;
            v8h w;
            if (hwv) {
                const float* src = &W_hh[(((size_t)l * H_) + j) * H_ + k0];
#pragma unroll
                for (int i = 0; i < 8; ++i) w[i] = (_Float16)src[i];
            } else if (l > 0) {
                const float* src = &W_ih[(((size_t)(l - 1) * H_) + j) * H_ + k0];
#pragma unroll
                for (int i = 0; i < 8; ++i) w[i] = (_Float16)src[i];
            } else {
#pragma unroll
                for (int i = 0; i < 8; ++i) w[i] = (_Float16)0.f;
            }
            wf[kt][nt] = w;
        }
    }

    // bias/w0: X-waves only (bias is folded into XP exactly as before).
    float bias[NT_][4], w0v[NT_][4];
    if (!hwv) {
#pragma unroll
        for (int nt = 0; nt < NT_; ++nt)
#pragma unroll
            for (int r = 0; r < 4; ++r) {
                const int j = nbase + nt * 16 + quad * 4 + r;
                bias[nt][r] = b_hh[l * H_ + j] +
                              ((l == 0) ? b_ih0[j] : b_ih[(l - 1) * H_ + j]);
                w0v[nt][r]  = (l == 0) ? W_ih0[j] : 0.f;
            }
    }

    unsigned* upprod = prod + ((l > 0 ? l - 1 : 0) * G_ + g);
    unsigned* myprod = prod + (l * G_ + g);
    unsigned* mycons = cons + (l * G_ + g);
    unsigned* dncons = cons + (((l < L_ - 1) ? l + 1 : l) * G_ + g);
    const unsigned R = (unsigned)rmask + 1u;
    u64* myring = ring + ((size_t)(l * G_ + g) * (size_t)R) * RQWS_;
    u64* upring = ring + ((size_t)((l > 0 ? l - 1 : 0) * G_ + g) * (size_t)R) * RQWS_;

    unsigned pSeen = 0, cSeen = 0;         // tid256 / tid320 private

    // critical-chain priority: each SIMD hosts 1 h-wave + 1 X-wave.
    if (hwv) __builtin_amdgcn_s_setprio(1);

    // ---- prologue ----
    if (l > 0) {
        // wait for slots 0 and 1, stage them into bufX[0], bufX[1] (X-only)
        if (tid == 256) {
            while (pSeen < 2u) {
                pSeen = __hip_atomic_load(upprod, __ATOMIC_RELAXED,
                                          __HIP_MEMORY_SCOPE_AGENT);
                if (pSeen < 2u) __builtin_amdgcn_s_sleep(2);
            }
        }
        __syncthreads();
        if (!hwv) {
#pragma unroll
            for (int sl = 0; sl < 2; ++sl)
#pragma unroll
                for (int jj = 0; jj < S_; ++jj)
#pragma unroll
                    for (int k = 0; k < 4; ++k) {
                        u64 v = __hip_atomic_load(
                            upring + (size_t)sl * RQWS_ + (size_t)jj * 1024 + eidx + k,
                            __ATOMIC_RELAXED, __HIP_MEMORY_SCOPE_AGENT);
                        *(u64*)&bufX[sl][jj][m_e][n_e + 4 * k] = v;
                    }
        }
        __syncthreads();
    }
    // X-waves: compute xps[0] (XP for superstep 0, t = 0..3)
    if (!hwv) {
#pragma unroll
        for (int jj = 0; jj < S_; ++jj) {
            v4f xpa[NT_];
#pragma unroll
            for (int nt = 0; nt < NT_; ++nt)
                xpa[nt] = (v4f){bias[nt][0], bias[nt][1], bias[nt][2], bias[nt][3]};
            if (l > 0) {
#pragma unroll
                for (int kt = 0; kt < 8; ++kt) {
                    v8h a = *(const v8h*)&bufX[0][jj][s16][kt * 32 + quad * 8];
#pragma unroll
                    for (int nt = 0; nt < NT_; ++nt)
                        xpa[nt] = __builtin_amdgcn_mfma_f32_16x16x32_f16(
                                      wf[kt][nt], a, xpa[nt], 0, 0, 0);
                }
            } else {
                const float xv = x[(size_t)(g * BM_ + s16) * T_ + jj];
#pragma unroll
                for (int nt = 0; nt < NT_; ++nt)
#pragma unroll
                    for (int r = 0; r < 4; ++r)
                        xpa[nt][r] = bias[nt][r] + xv * w0v[nt][r];
            }
#pragma unroll
            for (int nt = 0; nt < NT_; ++nt) {
                U64H pk;
#pragma unroll
                for (int r = 0; r < 4; ++r) pk.h[r] = (_Float16)xpa[nt][r];
                *(u64*)&xps[0][jj][s16][nbase + nt * 16 + quad * 4] = pk.u;
            }
        }
    }
    __syncthreads();   // lH zeros + xps[0] visible to all

    for (int s = 0; s < NS_; ++s) {
        const bool stOK = (l > 0) && (s + 2 < NS_);   // stage slot s+2 this superstep
        const bool xOK  = (s + 1 < NS_);              // compute XP for superstep s+1
        u64 pfv[S_][4];
        v4h xphv[S_][NT_];   // h-waves: this superstep's XP, hoisted at j0

#pragma unroll
        for (int j = 0; j < S_; ++j) {
            const int t = S_ * s + j;
            if (j == 1) bar_full(); else bar_lds();

            if (j == 0) {
                // slot s+1 finished copying during superstep s-1 -> free.
                if (tid == 448 && l > 0) {
                    const unsigned cv = (unsigned)((s + 2 <= NS_) ? s + 2 : NS_);
                    __hip_atomic_store(mycons, cv, __ATOMIC_RELAXED,
                                       __HIP_MEMORY_SCOPE_AGENT);
                }
                if (tid == 256 && stOK) {            // guards pf of slot s+2 at j1
                    const unsigned tgt = (unsigned)(s + 3);
                    while (pSeen < tgt) {
                        pSeen = __hip_atomic_load(upprod, __ATOMIC_RELAXED,
                                                  __HIP_MEMORY_SCOPE_AGENT);
                        if (pSeen < tgt) __builtin_amdgcn_s_sleep(2);
                    }
                }
                if (tid == 320 && l < L_ - 1 && s >= (int)R) {  // guards exports into slot s
                    const unsigned tgt = (unsigned)(s - (int)R + 1);
                    while (cSeen < tgt) {
                        cSeen = __hip_atomic_load(dncons, __ATOMIC_RELAXED,
                                                  __HIP_MEMORY_SCOPE_AGENT);
                        if (cSeen < tgt) __builtin_amdgcn_s_sleep(2);
                    }
                }
                if (hwv) {
                    // hoist all 4 steps' XP reads (xps[s&1] fully valid now)
#pragma unroll
                    for (int jj = 0; jj < S_; ++jj)
#pragma unroll
                        for (int nt = 0; nt < NT_; ++nt)
                            xphv[jj][nt] = *(const v4h*)
                                &xps[s & 1][jj][s16][nbase + nt * 16 + quad * 4];
                }
            }

            if (j == 1) {
                if (tid == 448 && l < L_ - 1 && s >= 1)
                    __hip_atomic_store(myprod, (unsigned)s, __ATOMIC_RELAXED,
                                       __HIP_MEMORY_SCOPE_AGENT); // slots 0..s-1 done
                if (stOK && !hwv) {   // prefetch slot s+2 -> regs (to bufX at j3)
                    const u64* base = upring + (size_t)((s + 2) & rmask) * RQWS_;
#pragma unroll
                    for (int jj = 0; jj < S_; ++jj)
#pragma unroll
                        for (int k = 0; k < 4; ++k)
                            pfv[jj][k] = __hip_atomic_load(
                                base + (size_t)jj * 1024 + eidx + k,
                                __ATOMIC_RELAXED, __HIP_MEMORY_SCOPE_AGENT);
                }
            }

            // ---- export h(t-1) (lag 1; lH[t&1] holds h(t-1)) — X-waves only ----
            if (!hwv && l < L_ - 1 && t > 0) {
                u64 e[4];
                e[0] = *(const u64*)&lH[t & 1][m_e][n_e];
                e[1] = *(const u64*)&lH[t & 1][m_e][n_e + 4];
                e[2] = *(const u64*)&lH[t & 1][m_e][n_e + 8];
                e[3] = *(const u64*)&lH[t & 1][m_e][n_e + 12];
                u64* d = myring + (size_t)(((t - 1) >> 2) & rmask) * RQWS_
                                + (size_t)((t - 1) & 3) * 1024 + eidx;
#pragma unroll
                for (int k = 0; k < 4; ++k)
                    __hip_atomic_store(d + k, e[k], __ATOMIC_RELAXED,
                                       __HIP_MEMORY_SCOPE_AGENT);
            }

            if (hwv) {
                // ---- h-wave: serial h-MFMA + epilogue (nothing else) ----
                v4f acc[NT_];
#pragma unroll
                for (int nt = 0; nt < NT_; ++nt) acc[nt] = (v4f){0.f, 0.f, 0.f, 0.f};
#pragma unroll
                for (int kt = 0; kt < 8; ++kt) {
                    v8h a = *(const v8h*)&lH[t & 1][s16][kt * 32 + quad * 8];
#pragma unroll
                    for (int nt = 0; nt < NT_; ++nt)
                        acc[nt] = __builtin_amdgcn_mfma_f32_16x16x32_f16(
                                      wf[kt][nt], a, acc[nt], 0, 0, 0);
                }
                // epilogue: relu(XP + acc) -> lH[(t+1)&1]; one b64 per nt
#pragma unroll
                for (int nt = 0; nt < NT_; ++nt) {
                    U64H pk;
#pragma unroll
                    for (int r = 0; r < 4; ++r) {
                        float v = (float)xphv[j][nt][r] + acc[nt][r];
                        v = fmaxf(v, 0.f);
                        pk.h[r] = (_Float16)v;
                    }
                    *(u64*)&lH[(t + 1) & 1][s16][nbase + nt * 16 + quad * 4] = pk.u;
                }
            } else if (xOK) {
                // ---- X-wave: XP[s+1][jj=j] = W_ih · X(4(s+1)+j)^T + bias ----
                v4f xpa[NT_];
#pragma unroll
                for (int nt = 0; nt < NT_; ++nt)
                    xpa[nt] = (v4f){bias[nt][0], bias[nt][1], bias[nt][2], bias[nt][3]};
                if (l > 0) {
#pragma unroll
                    for (int kt = 0; kt < 8; ++kt) {
                        v8h a = *(const v8h*)&bufX[(s + 1) & 1][j][s16][kt * 32 + quad * 8];
#pragma unroll
                        for (int nt = 0; nt < NT_; ++nt)
                            xpa[nt] = __builtin_amdgcn_mfma_f32_16x16x32_f16(
                                          wf[kt][nt], a, xpa[nt], 0, 0, 0);
                    }
                } else {
                    const float xv = x[(size_t)(g * BM_ + s16) * T_ + (S_ * (s + 1) + j)];
#pragma unroll
                    for (int nt = 0; nt < NT_; ++nt)
#pragma unroll
                        for (int r = 0; r < 4; ++r)
                            xpa[nt][r] = bias[nt][r] + xv * w0v[nt][r];
                }
#pragma unroll
                for (int nt = 0; nt < NT_; ++nt) {
                    U64H pk;
#pragma unroll
                    for (int r = 0; r < 4; ++r) pk.h[r] = (_Float16)xpa[nt][r];
                    *(u64*)&xps[(s + 1) & 1][j][s16][nbase + nt * 16 + quad * 4] = pk.u;
                }
            }

            if (j == S_ - 1 && stOK && !hwv) {
                // write slot s+2 into its bufX parity buffer (read starts next
                // superstep; the j0-top barrier orders it).
#pragma unroll
                for (int jj = 0; jj < S_; ++jj)
#pragma unroll
                    for (int k = 0; k < 4; ++k)
                        *(u64*)&bufX[s & 1][jj][m_e][n_e + 4 * k] = pfv[jj][k];
            }
        }
    }

    if (l < L_ - 1) {
        // tail: export h(T-1) (in lH[0]) — X-only, drain, publish all done
        if (!hwv) {
            u64* d = myring + (size_t)(((T_ - 1) >> 2) & rmask) * RQWS_
                            + (size_t)3 * 1024 + eidx;
#pragma unroll
            for (int k = 0; k < 4; ++k) {
                u64 e = *(const u64*)&lH[0][m_e][n_e + 4 * k];
                __hip_atomic_store(d + k, e, __ATOMIC_RELAXED,
                                   __HIP_MEMORY_SCOPE_AGENT);
            }
        }
        __syncthreads();   // full drain (vmcnt(0)) before publishing final prod
        if (tid == 448)
            __hip_atomic_store(myprod, (unsigned)NS_, __ATOMIC_RELAXED,
                               __HIP_MEMORY_SCOPE_AGENT);
    } else {
        __syncthreads();
        // final FC: out[b] = h_T[b] @ W_fc^T + b_fc; h_T in lH[0]
        if (tid < BM_ * C_) {
            const int bl = tid / C_;
            const int c  = tid % C_;
            float sum = b_fc[c];
            for (int k = 0; k < H_; ++k) sum += (float)lH[0][bl][k] * W_fc[c * H_ + k];
            out[(size_t)(g * BM_ + bl) * C_ + c] = sum;
        }
    }
}

extern "C" void kernel_launch(void* const* d_in, const int* in_sizes, int n_in,
                              void* d_out, int out_size, void* d_ws, size_t ws_size,
                              hipStream_t stream) {
    const float* x     = (const float*)d_in[0];
    const float* W_ih0 = (const float*)d_in[1];
    const float* b_ih0 = (const float*)d_in[2];
    const float* W_ih  = (const float*)d_in[3];
    const float* b_ih  = (const float*)d_in[4];
    const float* W_hh  = (const float*)d_in[5];
    const float* b_hh  = (const float*)d_in[6];
    const float* W_fc  = (const float*)d_in[7];
    const float* b_fc  = (const float*)d_in[8];
    float* out = (float*)d_out;

    const size_t cntBytes = (size_t)L_ * G_ * sizeof(unsigned);   // 640 B each
    unsigned* prod = (unsigned*)d_ws;
    unsigned* cons = (unsigned*)((char*)d_ws + cntBytes);
    u64* ring      = (u64*)((char*)d_ws + 2 * cntBytes);

    // ring slots per link, by available workspace (32 KB per slot per link)
    const size_t slotBytes = (size_t)RQWS_ * 8;                   // 32 KB
    const size_t base = 2 * cntBytes;
    int R = 4;                                                    // 21 MB
    if (ws_size >= base + (size_t)L_ * G_ * 16 * slotBytes) R = 16;      // 84 MB
    else if (ws_size >= base + (size_t)L_ * G_ * 8 * slotBytes) R = 8;   // 42 MB

    hipMemsetAsync(d_ws, 0, 2 * cntBytes, stream);

    rnn_wavefront<<<dim3(L_ * G_), dim3(TPB_), 0, stream>>>(
        x, W_ih0, b_ih0, W_ih, b_ih, W_hh, b_hh, W_fc, b_fc,
        out, prod, cons, ring, R - 1);
}

// Round 7
// 1521.678 us; speedup vs baseline: 1.0627x; 1.0627x over previous
//
#include <hip/hip_runtime.h>
#include <hip/hip_fp16.h>

// Wavefront-pipelined 20-layer ReLU RNN for MI355X — round 19.
// = round 18's barrier-free dataflow design, LDS-budgeted (r18 failed compile
// at 207KB LDS). Fixes: xps lead-2 -> lead-1 (2-deep), bufX full-slot ->
// half-slot ping-pong (2 step-buffers, X-internal rendezvous), strides 264.
// LDS = 67584(lH[8]) + 66560(xps[2]) + 16896(bufX[2]) + flags = ~151KB.
// Rationale (r13-r17): every throughput resource exonerated; the ~2830cy/step
// is 8-wave per-step s_barrier choreography (pollers' remote loads, exports,
// staging all rendezvous every step). This design has NO s_barrier in the hot
// path: h-waves 0-3 run a pure-local recurrence synced by packed LDS flags;
// X-waves 4-7 do exports (lane-contiguous stores, r17 lesson), ring staging,
// XP GEMM one superstep ahead, and all remote protocol.
// Arithmetic bit-identical to r12 -> absmax must stay 6.103516e-05.

#define B_    128
#define T_    784
#define H_    256
#define L_    20
#define C_    10
#define G_    8      // batch slices
#define BM_   16     // batch rows per block
#define S_    4      // timesteps per superstep / ring slot
#define NS_   196    // T_/S_
#define SW_   264    // lH/bufX row stride in halves (132 dw = 4 mod 32; 16B-aligned)
#define XSW_  260    // xps row stride in halves (130 dw = 2 mod 32; 8B-aligned)
#define RQWS_ 4096   // u64 words per ring slot (4 steps x 16 rows x 64 u64)
#define TPB_  512
#define NT_   4      // 16-col n-tiles per wave

typedef _Float16 v8h __attribute__((ext_vector_type(8)));
typedef _Float16 v4h __attribute__((ext_vector_type(4)));
typedef float    v4f __attribute__((ext_vector_type(4)));
typedef unsigned long long u64;

union U64H { u64 u; _Float16 h[4]; };

__device__ __forceinline__ void lgkm0() { asm volatile("s_waitcnt lgkmcnt(0)" ::: "memory"); }
__device__ __forceinline__ void vm0()   { asm volatile("s_waitcnt vmcnt(0)"   ::: "memory"); }
__device__ __forceinline__ void cbar()  { asm volatile("" ::: "memory"); }

__device__ __forceinline__ void flagst(unsigned* p, unsigned v) {
    cbar();
    __hip_atomic_store(p, v, __ATOMIC_RELAXED, __HIP_MEMORY_SCOPE_WORKGROUP);
}
// tight spin: all 4 flags >= tgt (two b64 loads per iter)
__device__ __forceinline__ void spin4(const unsigned* f, unsigned tgt) {
    const volatile u64* p = (const volatile u64*)f;
    for (;;) {
        u64 a = p[0], b = p[1];
        if ((unsigned)a >= tgt && (unsigned)(a >> 32) >= tgt &&
            (unsigned)b >= tgt && (unsigned)(b >> 32) >= tgt) break;
    }
    cbar();
}
// sleepy spin (X-waves waiting on h): don't hammer LDS while h computes
__device__ __forceinline__ void spin4s(const unsigned* f, unsigned tgt) {
    const volatile u64* p = (const volatile u64*)f;
    for (;;) {
        u64 a = p[0], b = p[1];
        if ((unsigned)a >= tgt && (unsigned)(a >> 32) >= tgt &&
            (unsigned)b >= tgt && (unsigned)(b >> 32) >= tgt) break;
        __builtin_amdgcn_s_sleep(1);
    }
    cbar();
}
__device__ __forceinline__ u64 ringld(const u64* p) {
    return __hip_atomic_load(p, __ATOMIC_RELAXED, __HIP_MEMORY_SCOPE_AGENT);
}
__device__ __forceinline__ void ringst(u64* p, u64 v) {
    __hip_atomic_store(p, v, __ATOMIC_RELAXED, __HIP_MEMORY_SCOPE_AGENT);
}
__device__ __forceinline__ unsigned remld(const unsigned* p) {
    return __hip_atomic_load(p, __ATOMIC_RELAXED, __HIP_MEMORY_SCOPE_AGENT);
}
__device__ __forceinline__ void rempub(unsigned* p, unsigned v) {
    __hip_atomic_store(p, v, __ATOMIC_RELAXED, __HIP_MEMORY_SCOPE_AGENT);
}
__device__ __forceinline__ void rpoll(const unsigned* p, unsigned tgt) {
    while (remld(p) < tgt) __builtin_amdgcn_s_sleep(2);
}

__global__ __launch_bounds__(TPB_, 2)
void rnn_wavefront(const float* __restrict__ x,
                   const float* __restrict__ W_ih0,
                   const float* __restrict__ b_ih0,
                   const float* __restrict__ W_ih,
                   const float* __restrict__ b_ih,
                   const float* __restrict__ W_hh,
                   const float* __restrict__ b_hh,
                   const float* __restrict__ W_fc,
                   const float* __restrict__ b_fc,
                   float* __restrict__ out,
                   unsigned* __restrict__ prod,    // [L_][G_]: slots exported
                   unsigned* __restrict__ cons,    // [L_][G_]: slots consumed
                   u64* __restrict__ ring,         // [L_][G_][R][RQWS_]
                   int rmask)
{
    const int l    = blockIdx.x >> 3;
    const int g    = blockIdx.x & 7;
    const int tid  = threadIdx.x;
    const int lane = tid & 63;
    const int wave = tid >> 6;          // 0..7
    const bool hrole = wave < 4;        // waves 0-3: h; waves 4-7: X
    const int wsub = hrole ? wave : wave - 4;
    const int quad = lane >> 4;
    const int s16  = lane & 15;
    const int nbase = wsub * 64;        // 64 output columns per wave
    const int xtid  = tid & 255;        // X staging/export thread id (0..255)

    // lH: 8-deep y history (y(t) lives in lH[(t+1)&7]).
    __shared__ __align__(16) _Float16 lH[8][BM_][SW_];
    // xps: 2-deep XP buffers; superstep s in xps[s&1] (lead-1).
    __shared__ __align__(16) _Float16 xps[2][S_][BM_][XSW_];
    // bufX: half-slot ping-pong (2 step-buffers; jj uses bufX[jj&1]).
    __shared__ __align__(16) _Float16 bufX[2][BM_][SW_];
    __shared__ __align__(16) unsigned hflag[4];   // h-wave finished step t -> t+1
    __shared__ __align__(16) unsigned xdone4[4];  // export reads of slot sg-1 done -> sg+1
    __shared__ __align__(16) unsigned xpdone4[4]; // xps for superstep q ready -> q+1
    __shared__ __align__(16) unsigned xsflag[4];  // staging halves: slot q -> 2q+1, 2q+2
    __shared__ __align__(16) unsigned xcflag[4];  // computes of half A of slot q -> q+1
    __shared__ __align__(16) unsigned xeflag[4];  // all computes of slot q -> q+1
    __shared__ __align__(16) unsigned xvflag[4];  // vm-drained iteration sg -> sg+1

    for (int i = tid; i < BM_ * SW_; i += TPB_) (&lH[0][0][0])[i] = (_Float16)0.f;
    if (tid < 4) {
        hflag[tid] = 0; xdone4[tid] = 0; xpdone4[tid] = 0;
        xsflag[tid] = 0; xcflag[tid] = 0; xeflag[tid] = 0; xvflag[tid] = 0;
    }

    // ---- weights: h-waves hold W_hh[l], X-waves hold W_ih[l-1] ----
    v8h wf[8][NT_];
#pragma unroll
    for (int kt = 0; kt < 8; ++kt) {
        const int k0 = kt * 32 + quad * 8;
#pragma unroll
        for (int nt = 0; nt < NT_; ++nt) {
            const int j = nbase + nt * 16 + s16;
            v8h w;
            if (hrole) {
                const float* src = &W_hh[(((size_t)l * H_) + j) * H_ + k0];
#pragma unroll
                for (int i = 0; i < 8; ++i) w[i] = (_Float16)src[i];
            } else if (l > 0) {
                const float* src = &W_ih[(((size_t)(l - 1) * H_) + j) * H_ + k0];
#pragma unroll
                for (int i = 0; i < 8; ++i) w[i] = (_Float16)src[i];
            } else {
#pragma unroll
                for (int i = 0; i < 8; ++i) w[i] = (_Float16)0.f;
            }
            wf[kt][nt] = w;
        }
    }

    // bias: X-waves (l>0) fold b_ih+b_hh into XP; l==0 h-waves do it locally.
    float bias[NT_][4], w0v[NT_][4];
    if ((!hrole && l > 0) || (hrole && l == 0)) {
#pragma unroll
        for (int nt = 0; nt < NT_; ++nt)
#pragma unroll
            for (int r = 0; r < 4; ++r) {
                const int j = nbase + nt * 16 + quad * 4 + r;
                bias[nt][r] = b_hh[l * H_ + j] +
                              ((l == 0) ? b_ih0[j] : b_ih[(l - 1) * H_ + j]);
                w0v[nt][r]  = (l == 0) ? W_ih0[j] : 0.f;
            }
    }

    unsigned* upprod = prod + ((l > 0 ? l - 1 : 0) * G_ + g);
    unsigned* myprod = prod + (l * G_ + g);
    unsigned* mycons = cons + (l * G_ + g);                    // downstream's consumption of ring(l)
    unsigned* upcons = cons + ((l > 0 ? l - 1 : 0) * G_ + g);  // we consume ring(l-1)
    const unsigned R = (unsigned)rmask + 1u;
    u64* myring = ring + ((size_t)(l * G_ + g) * (size_t)R) * RQWS_;
    u64* upring = ring + ((size_t)((l > 0 ? l - 1 : 0) * G_ + g) * (size_t)R) * RQWS_;

    __syncthreads();   // zeros + flags visible; the only block barrier

    // X helpers (lambdas; all loops static)
    auto xstage = [&](const u64* sbp, int half) {   // half 0: jj 0,1; half 1: jj 2,3
        u64 sv[8];
#pragma unroll
        for (int k = 0; k < 8; ++k)
            sv[k] = ringld(sbp + (size_t)(half * 2048 + xtid + 256 * k));
#pragma unroll
        for (int k = 0; k < 8; ++k) {
            const int idx = half * 2048 + xtid + 256 * k;
            const int rr  = idx & 1023;
            *(u64*)&bufX[(idx >> 10) & 1][rr & 15][(rr >> 4) * 4] = sv[k];
        }
    };
    auto xcompute = [&](int q, int jj) {            // xps[q&1][jj] from bufX[jj&1]
        v4f xpa[NT_];
#pragma unroll
        for (int nt = 0; nt < NT_; ++nt)
            xpa[nt] = (v4f){bias[nt][0], bias[nt][1], bias[nt][2], bias[nt][3]};
#pragma unroll
        for (int kt = 0; kt < 8; ++kt) {
            v8h a = *(const v8h*)&bufX[jj & 1][s16][kt * 32 + quad * 8];
#pragma unroll
            for (int nt = 0; nt < NT_; ++nt)
                xpa[nt] = __builtin_amdgcn_mfma_f32_16x16x32_f16(
                              wf[kt][nt], a, xpa[nt], 0, 0, 0);
        }
#pragma unroll
        for (int nt = 0; nt < NT_; ++nt) {
            U64H pk;
#pragma unroll
            for (int r = 0; r < 4; ++r) pk.h[r] = (_Float16)xpa[nt][r];
            *(u64*)&xps[q & 1][jj][s16][nbase + nt * 16 + quad * 4] = pk.u;
        }
    };
    auto xslot = [&](int q) {                       // stage+compute upstream slot q
        rpoll(upprod, (unsigned)(q + 1));
        spin4(xeflag, (unsigned)q);                 // prev slot's computes done
        const u64* sbp = upring + (size_t)(q & rmask) * RQWS_;
        xstage(sbp, 0);
        lgkm0(); flagst(&xsflag[wsub], (unsigned)(2 * q + 1));
        spin4(xsflag, (unsigned)(2 * q + 1));
        xcompute(q, 0); xcompute(q, 1);
        lgkm0(); flagst(&xcflag[wsub], (unsigned)(q + 1));
        spin4(xcflag, (unsigned)(q + 1));           // all A-reads done
        xstage(sbp, 1);
        lgkm0(); flagst(&xsflag[wsub], (unsigned)(2 * q + 2));
        spin4(xsflag, (unsigned)(2 * q + 2));
        xcompute(q, 2); xcompute(q, 3);
        lgkm0();
        flagst(&xpdone4[wsub], (unsigned)(q + 1));  // xps for superstep q ready
        flagst(&xeflag[wsub], (unsigned)(q + 1));
    };

    if (hrole) {
        // ================= h-waves: pure-local recurrence =================
        float xnf[4];
        v4h xphv[4][NT_];
        if (l == 0) {
            const float* xrow = x + (size_t)(g * BM_ + s16) * T_;
#pragma unroll
            for (int jj = 0; jj < 4; ++jj) xnf[jj] = xrow[jj];
        }
        for (int s = 0; s < NS_; ++s) {
#pragma unroll
            for (int j = 0; j < S_; ++j) {
                const int t = 4 * s + j;
                spin4(hflag, (unsigned)t);               // all waves wrote y(t-1)
                if (j == 0) {
                    if (l < L_ - 1) spin4(xdone4, (unsigned)s);       // slot s-2 export reads done
                    if (l > 0)      spin4(xpdone4, (unsigned)(s + 1)); // xps[s] ready
                    if (l == 0) {
#pragma unroll
                        for (int jj = 0; jj < 4; ++jj)
#pragma unroll
                            for (int nt = 0; nt < NT_; ++nt)
#pragma unroll
                                for (int r = 0; r < 4; ++r)
                                    xphv[jj][nt][r] =
                                        (_Float16)(bias[nt][r] + xnf[jj] * w0v[nt][r]);
                    }
                }
                if (j == 1 && l == 0 && s + 1 < NS_) {
                    const float* xrow = x + (size_t)(g * BM_ + s16) * T_ + 4 * (s + 1);
#pragma unroll
                    for (int jj = 0; jj < 4; ++jj) xnf[jj] = xrow[jj];
                }

                v4h xph[NT_];
                if (l > 0) {
#pragma unroll
                    for (int nt = 0; nt < NT_; ++nt)
                        xph[nt] = *(const v4h*)
                            &xps[s & 1][j][s16][nbase + nt * 16 + quad * 4];
                } else {
#pragma unroll
                    for (int nt = 0; nt < NT_; ++nt) xph[nt] = xphv[j][nt];
                }

                v4f acc[NT_];
#pragma unroll
                for (int nt = 0; nt < NT_; ++nt) acc[nt] = (v4f){0.f, 0.f, 0.f, 0.f};
#pragma unroll
                for (int kt = 0; kt < 8; ++kt) {
                    v8h a = *(const v8h*)&lH[t & 7][s16][kt * 32 + quad * 8];
#pragma unroll
                    for (int nt = 0; nt < NT_; ++nt)
                        acc[nt] = __builtin_amdgcn_mfma_f32_16x16x32_f16(
                                      wf[kt][nt], a, acc[nt], 0, 0, 0);
                }
#pragma unroll
                for (int nt = 0; nt < NT_; ++nt) {
                    U64H pk;
#pragma unroll
                    for (int r = 0; r < 4; ++r) {
                        float v = (float)xph[nt][r] + acc[nt][r];
                        v = fmaxf(v, 0.f);
                        pk.h[r] = (_Float16)v;
                    }
                    *(u64*)&lH[(t + 1) & 7][s16][nbase + nt * 16 + quad * 4] = pk.u;
                }
                lgkm0();
                flagst(&hflag[wave], (unsigned)(t + 1));
            }
        }
        if (l == L_ - 1) {
            spin4(hflag, (unsigned)T_);   // all waves wrote y(783) -> lH[0]
            lgkm0();
            if (tid < BM_ * C_) {
                const int bl = tid / C_;
                const int c  = tid % C_;
                float sum = b_fc[c];
                for (int k = 0; k < H_; ++k)
                    sum += (float)lH[0][bl][k] * W_fc[c * H_ + k];
                out[(size_t)(g * BM_ + bl) * C_ + c] = sum;
            }
        }
    } else {
        // ============ X-waves: exports, staging, XP GEMM, protocol ============
        if (l > 0) {                        // prologue: slot 0 -> xps[0]
            xslot(0);
            vm0();
            if (tid == 256) rempub(upcons, 1u);
        }
        for (int sg = 0; sg <= NS_; ++sg) {
            spin4s(hflag, (unsigned)(4 * sg));          // h finished superstep sg-1

            // exports: slot e = sg-1 (y(t) lives in lH[(t+1)&7]); lane-contiguous
            if (l < L_ - 1 && sg >= 1) {
                const int e = sg - 1;
                if (e >= (int)R) rpoll(mycons, (unsigned)(e - (int)R + 1));
                u64* db = myring + (size_t)(e & rmask) * RQWS_;
#pragma unroll
                for (int jj = 0; jj < 4; ++jj) {
                    const int buf = (4 * e + jj + 1) & 7;
                    u64 ev[4];
#pragma unroll
                    for (int k = 0; k < 4; ++k) {
                        const int rr = xtid + 256 * k;
                        ev[k] = *(const u64*)&lH[buf][rr & 15][(rr >> 4) * 4];
                    }
#pragma unroll
                    for (int k = 0; k < 4; ++k)
                        ringst(db + (size_t)jj * 1024 + (size_t)(xtid + 256 * k), ev[k]);
                }
                lgkm0();
            }
            flagst(&xdone4[wsub], (unsigned)(sg + 1));  // export reads done -> h may overwrite

            // stage + compute upstream slot sg+1 -> xps[(sg+1)&1] (lead-1)
            if (l > 0 && sg + 1 <= NS_ - 1) xslot(sg + 1);

            // drain own stores/loads, rendezvous X-waves, publish protocol
            vm0();
            flagst(&xvflag[wsub], (unsigned)(sg + 1));
            spin4(xvflag, (unsigned)(sg + 1));
            if (tid == 256) {
                if (l < L_ - 1 && sg >= 1) rempub(myprod, (unsigned)sg);
                if (l > 0 && sg + 1 <= NS_ - 1) rempub(upcons, (unsigned)(sg + 2));
            }
        }
    }
}

extern "C" void kernel_launch(void* const* d_in, const int* in_sizes, int n_in,
                              void* d_out, int out_size, void* d_ws, size_t ws_size,
                              hipStream_t stream) {
    const float* x     = (const float*)d_in[0];
    const float* W_ih0 = (const float*)d_in[1];
    const float* b_ih0 = (const float*)d_in[2];
    const float* W_ih  = (const float*)d_in[3];
    const float* b_ih  = (const float*)d_in[4];
    const float* W_hh  = (const float*)d_in[5];
    const float* b_hh  = (const float*)d_in[6];
    const float* W_fc  = (const float*)d_in[7];
    const float* b_fc  = (const float*)d_in[8];
    float* out = (float*)d_out;

    const size_t cntBytes = (size_t)L_ * G_ * sizeof(unsigned);   // 640 B each
    unsigned* prod = (unsigned*)d_ws;
    unsigned* cons = (unsigned*)((char*)d_ws + cntBytes);
    u64* ring      = (u64*)((char*)d_ws + 2 * cntBytes);

    const size_t slotBytes = (size_t)RQWS_ * 8;                   // 32 KB
    const size_t base = 2 * cntBytes;
    int R = 4;                                                    // 21 MB
    if (ws_size >= base + (size_t)L_ * G_ * 16 * slotBytes) R = 16;      // 84 MB
    else if (ws_size >= base + (size_t)L_ * G_ * 8 * slotBytes) R = 8;   // 42 MB

    (void)hipMemsetAsync(d_ws, 0, 2 * cntBytes, stream);

    rnn_wavefront<<<dim3(L_ * G_), dim3(TPB_), 0, stream>>>(
        x, W_ih0, b_ih0, W_ih, b_ih, W_hh, b_hh, W_fc, b_fc,
        out, prod, cons, ring, R - 1);
}